// Round 21
// baseline (129.085 us; speedup 1.0000x reference)
//
#include <hip/hip_runtime.h>
#include <hip/hip_bf16.h>

#define NEG_SLOPE 0.2f
#define BN_EPS 1e-5f

typedef _Float16 half8 __attribute__((ext_vector_type(8)));
typedef _Float16 half4v __attribute__((ext_vector_type(4)));
typedef _Float16 half2v __attribute__((ext_vector_type(2)));
typedef float f32x4 __attribute__((ext_vector_type(4)));

// ---------- fast zero of scratch + output ----------
__global__ void k_zero(uint4* __restrict__ p, int n4, uint4* __restrict__ q, int m4) {
    int i = blockIdx.x * blockDim.x + threadIdx.x;
    if (i < n4) p[i] = (uint4){0u, 0u, 0u, 0u};
    else if (i < n4 + m4) q[i - n4] = (uint4){0u, 0u, 0u, 0u};
}

// ---------- setup: coef (blk0), gbounds (blk1), w2t tile-transpose (blk2..33),
//            edge degree count (blk34..) ----------
__global__ void k_setup(const float* __restrict__ W1, const float* __restrict__ asw,
                        const float* __restrict__ adw, float* __restrict__ coef,
                        const float* __restrict__ W2, _Float16* __restrict__ w2t,
                        const int* __restrict__ batch, int N, int G, int* __restrict__ gb,
                        const int* __restrict__ ei, int E, int E2, int* __restrict__ cnt) {
    __shared__ float tile[32][33];
    int bid = blockIdx.x, t = threadIdx.x;
    if (bid == 0) {
        float w0 = W1[t], w1 = W1[256 + t], as = asw[t], ad = adw[t];
        float v0 = w0 * as, v1 = w1 * as, v2 = w0 * ad, v3 = w1 * ad;
        for (int o = 32; o; o >>= 1) {
            v0 += __shfl_down(v0, o); v1 += __shfl_down(v1, o);
            v2 += __shfl_down(v2, o); v3 += __shfl_down(v3, o);
        }
        if ((t & 63) == 0) {
            int h = t >> 6;
            coef[h * 4 + 0] = v0; coef[h * 4 + 1] = v1;
            coef[h * 4 + 2] = v2; coef[h * 4 + 3] = v3;
        }
    } else if (bid == 1) {
        int g = t;
        if (g <= G) {
            int lo = 0, hi = N;
            while (lo < hi) { int mid = (lo + hi) >> 1; if (batch[mid] < g) lo = mid + 1; else hi = mid; }
            gb[g] = lo;
        }
    } else if (bid < 34) {
        int tl = bid - 2;
        int r0 = (tl >> 2) * 32, c0 = (tl & 3) * 32;
        int tr = t >> 5, tc = t & 31;
        #pragma unroll
        for (int i = 0; i < 4; i++)
            tile[tr + 8 * i][tc] = W2[(size_t)(r0 + tr + 8 * i) * 128 + c0 + tc];
        __syncthreads();
        #pragma unroll
        for (int i = 0; i < 4; i++)
            w2t[(size_t)(c0 + tr + 8 * i) * 256 + r0 + tc] = (_Float16)tile[tc][tr + 8 * i];
    } else {
        int i = (bid - 34) * 256 + t;
        if (i < E2) {
            int d = (i < E) ? ei[E + i] : (i - E);
            atomicAdd(&cnt[d], 1);
        }
    }
}

// ---------- hierarchical scan, stage 1 ----------
__global__ void k_scan1(const int* __restrict__ cnt, int* __restrict__ rp,
                        int* __restrict__ bsums, int n) {
    __shared__ int s[1024];
    int i = blockIdx.x * 1024 + threadIdx.x;
    int v = (i < n) ? cnt[i] : 0;
    s[threadIdx.x] = v;
    __syncthreads();
    for (int o = 1; o < 1024; o <<= 1) {
        int t = (threadIdx.x >= o) ? s[threadIdx.x - o] : 0;
        __syncthreads();
        s[threadIdx.x] += t;
        __syncthreads();
    }
    if (i < n) rp[i] = s[threadIdx.x] - v;
    if (threadIdx.x == 1023) bsums[blockIdx.x] = s[1023];
}

// ---------- stage 2: wave-parallel prefix of bsums + offset add ----------
__global__ void k_scan2f(int* __restrict__ rp, const int* __restrict__ bsums,
                         int n, int total, int nb) {
    __shared__ int boff;
    if (threadIdx.x < 64) {
        int lane = threadIdx.x;
        int v = (lane < nb) ? bsums[lane] : 0;
        #pragma unroll
        for (int o = 1; o < 64; o <<= 1) {
            int t = __shfl_up(v, o);
            if (lane >= o) v += t;
        }
        int ex = __shfl_up(v, 1);
        if (lane == (int)blockIdx.x) boff = (blockIdx.x == 0) ? 0 : ex;
    }
    __syncthreads();
    int i = blockIdx.x * 1024 + threadIdx.x;
    if (i < n) rp[i] += boff;
    if (blockIdx.x == 0 && threadIdx.x == 0) rp[n] = total;
}

// ---------- scatter: consumes cnt (deg) via atomicSub ----------
__global__ void k_scatter(const int* __restrict__ ei, int E, int E2,
                          const int* __restrict__ rp, int* __restrict__ cnt,
                          int* __restrict__ esrc) {
    int i = blockIdx.x * blockDim.x + threadIdx.x;
    if (i >= E2) return;
    int s, d;
    if (i < E) { s = ei[i]; d = ei[E + i]; } else { s = d = i - E; }
    int old = atomicSub(&cnt[d], 1);
    esrc[rp[d] + old - 1] = s;
}

// ---------- Layer 1 aggregation (rank-2), 2-edge unrolled + BN1 stats ----------
__global__ void k_agg1r(const int* __restrict__ rp, const int* __restrict__ esrc,
                        const float* __restrict__ x, const float* __restrict__ coef,
                        float* __restrict__ uv, float* __restrict__ stats, int N) {
    __shared__ float sred[4][20];
    int tid = threadIdx.x, lane = tid & 63, wid = tid >> 6;
    int n = blockIdx.x * blockDim.x + tid;
    float st[20];
    #pragma unroll
    for (int i = 0; i < 20; i++) st[i] = 0.f;

    if (n < N) {
        float c[16];
        #pragma unroll
        for (int i = 0; i < 16; i++) c[i] = coef[i];
        float2 xn = ((const float2*)x)[n];
        float ad[4], den[4], sx[4], sy[4];
        #pragma unroll
        for (int h = 0; h < 4; h++) {
            ad[h] = fmaf(xn.x, c[h * 4 + 2], xn.y * c[h * 4 + 3]);
            den[h] = 0.f; sx[h] = 0.f; sy[h] = 0.f;
        }
        int beg = rp[n], end = rp[n + 1];
        int k = beg;
        for (; k + 1 < end; k += 2) {
            int s0 = esrc[k], s1 = esrc[k + 1];
            float2 xv0 = ((const float2*)x)[s0];
            float2 xv1 = ((const float2*)x)[s1];
            #pragma unroll
            for (int h = 0; h < 4; h++) {
                float e0 = fmaf(xv0.x, c[h * 4 + 0], xv0.y * c[h * 4 + 1]) + ad[h];
                float e1 = fmaf(xv1.x, c[h * 4 + 0], xv1.y * c[h * 4 + 1]) + ad[h];
                e0 = e0 > 0.f ? e0 : NEG_SLOPE * e0;
                e1 = e1 > 0.f ? e1 : NEG_SLOPE * e1;
                float w0 = __expf(e0), w1 = __expf(e1);
                den[h] += w0 + w1;
                sx[h] = fmaf(w0, xv0.x, sx[h]); sy[h] = fmaf(w0, xv0.y, sy[h]);
                sx[h] = fmaf(w1, xv1.x, sx[h]); sy[h] = fmaf(w1, xv1.y, sy[h]);
            }
        }
        if (k < end) {
            int s = esrc[k];
            float2 xv = ((const float2*)x)[s];
            #pragma unroll
            for (int h = 0; h < 4; h++) {
                float e = fmaf(xv.x, c[h * 4 + 0], xv.y * c[h * 4 + 1]) + ad[h];
                e = e > 0.f ? e : NEG_SLOPE * e;
                float w = __expf(e);
                den[h] += w; sx[h] = fmaf(w, xv.x, sx[h]); sy[h] = fmaf(w, xv.y, sy[h]);
            }
        }
        float* o = uv + (size_t)n * 8;
        #pragma unroll
        for (int h = 0; h < 4; h++) {
            float inv = 1.f / (den[h] + 1e-16f);
            float u = sx[h] * inv, v = sy[h] * inv;
            o[h] = u; o[4 + h] = v;
            st[h] = u; st[4 + h] = v;
            st[8 + h] = u * u; st[12 + h] = v * v; st[16 + h] = u * v;
        }
    }
    #pragma unroll
    for (int i = 0; i < 20; i++)
        for (int o = 32; o; o >>= 1) st[i] += __shfl_down(st[i], o);
    if (lane == 0)
        #pragma unroll
        for (int i = 0; i < 20; i++) sred[wid][i] = st[i];
    __syncthreads();
    if (tid < 20)
        atomicAdd(&stats[tid], sred[0][tid] + sred[1][tid] + sred[2][tid] + sred[3][tid]);
}

// ---------- Layer 2 GEMM via MFMA; 512 threads / 128 rows per block ----------
__global__ __launch_bounds__(512) void k_gemm2(
        const float* __restrict__ uv, const float* __restrict__ stats,
        const float* __restrict__ W1, const float* __restrict__ b1,
        const float* __restrict__ gamma, const float* __restrict__ beta,
        const _Float16* __restrict__ w2t,
        const float* __restrict__ asw, const float* __restrict__ adw,
        _Float16* __restrict__ g2h, float* __restrict__ as2,
        float* __restrict__ ad2, int N) {
    __shared__ _Float16 bs[128][136];
    __shared__ float abcs[768];
    int tid = threadIdx.x, wid = tid >> 6, l = tid & 63;
    int kg = l >> 4, ln = l & 15;
    int n0w = blockIdx.x * 128 + wid * 16;

    if (tid < 256) {
        int j = tid, h = j >> 6;
        float w0 = W1[j], w1 = W1[256 + j], b = b1[j];
        float Su = stats[h], Sv = stats[4 + h], Suu = stats[8 + h],
              Svv = stats[12 + h], Suv = stats[16 + h];
        float fN = (float)N;
        float lin = fmaf(w0, Su, w1 * Sv);
        float mean = lin / fN + b;
        float sq = w0 * w0 * Suu + w1 * w1 * Svv + 2.f * w0 * w1 * Suv + 2.f * b * lin + fN * b * b;
        float var = sq / fN - mean * mean;
        float sc = rsqrtf(var + BN_EPS) * gamma[j];
        float sh = beta[j] - mean * sc;
        abcs[j] = sc * w0;
        abcs[256 + j] = sc * w1;
        abcs[512 + j] = fmaf(sc, b, sh);
    }

    int arow = n0w + ln;
    float uvr[8];
    if (arow < N) {
        const float4* p = (const float4*)(uv + (size_t)arow * 8);
        float4 t0 = p[0], t1 = p[1];
        uvr[0] = t0.x; uvr[1] = t0.y; uvr[2] = t0.z; uvr[3] = t0.w;
        uvr[4] = t1.x; uvr[5] = t1.y; uvr[6] = t1.z; uvr[7] = t1.w;
    } else {
        #pragma unroll
        for (int i = 0; i < 8; i++) uvr[i] = 0.f;
    }

    f32x4 acc[8];
    #pragma unroll
    for (int ct = 0; ct < 8; ct++) acc[ct] = (f32x4){0.f, 0.f, 0.f, 0.f};

    int sc_ = tid >> 2, q = tid & 3;
    for (int s = 0; s < 2; s++) {
        #pragma unroll
        for (int j = 0; j < 4; j++) {
            *(half8*)&bs[sc_][q * 32 + j * 8] =
                *(const half8*)&w2t[(size_t)sc_ * 256 + s * 128 + q * 32 + j * 8];
        }
        __syncthreads();
        #pragma unroll
        for (int kt4 = 0; kt4 < 4; kt4++) {
            int kt = s * 4 + kt4;
            int h = kt >> 1;
            float u = uvr[h], v = uvr[4 + h];
            int kb = kt * 32 + kg * 8;
            float4 A0a = *(const float4*)&abcs[kb],       A0b = *(const float4*)&abcs[kb + 4];
            float4 A1a = *(const float4*)&abcs[256 + kb], A1b = *(const float4*)&abcs[256 + kb + 4];
            float4 A2a = *(const float4*)&abcs[512 + kb], A2b = *(const float4*)&abcs[512 + kb + 4];
            half8 af;
            float y;
            y = fmaf(A0a.x, u, fmaf(A1a.x, v, A2a.x)); af[0] = (_Float16)(y > 0.f ? y : __expf(y) - 1.f);
            y = fmaf(A0a.y, u, fmaf(A1a.y, v, A2a.y)); af[1] = (_Float16)(y > 0.f ? y : __expf(y) - 1.f);
            y = fmaf(A0a.z, u, fmaf(A1a.z, v, A2a.z)); af[2] = (_Float16)(y > 0.f ? y : __expf(y) - 1.f);
            y = fmaf(A0a.w, u, fmaf(A1a.w, v, A2a.w)); af[3] = (_Float16)(y > 0.f ? y : __expf(y) - 1.f);
            y = fmaf(A0b.x, u, fmaf(A1b.x, v, A2b.x)); af[4] = (_Float16)(y > 0.f ? y : __expf(y) - 1.f);
            y = fmaf(A0b.y, u, fmaf(A1b.y, v, A2b.y)); af[5] = (_Float16)(y > 0.f ? y : __expf(y) - 1.f);
            y = fmaf(A0b.z, u, fmaf(A1b.z, v, A2b.z)); af[6] = (_Float16)(y > 0.f ? y : __expf(y) - 1.f);
            y = fmaf(A0b.w, u, fmaf(A1b.w, v, A2b.w)); af[7] = (_Float16)(y > 0.f ? y : __expf(y) - 1.f);
            int klo = kt4 * 32 + kg * 8;
            #pragma unroll
            for (int ct = 0; ct < 8; ct++) {
                half8 bf = *(const half8*)&bs[ct * 16 + ln][klo];
                acc[ct] = __builtin_amdgcn_mfma_f32_16x16x32_f16(af, bf, acc[ct], 0, 0, 0);
            }
        }
        __syncthreads();
    }

    _Float16 (*tbuf)[16][136] = (_Float16 (*)[16][136])&bs[0][0];
    #pragma unroll
    for (int ct = 0; ct < 8; ct++)
        #pragma unroll
        for (int r = 0; r < 4; r++)
            tbuf[wid][kg * 4 + r][ct * 16 + ln] = (_Float16)acc[ct][r];
    __syncthreads();

    int rr = l >> 2, cq = l & 3;
    int node = n0w + rr;
    half8 hv[4];
    #pragma unroll
    for (int j = 0; j < 4; j++) hv[j] = *(const half8*)&tbuf[wid][rr][cq * 32 + j * 8];
    float ps = 0.f, pd = 0.f;
    #pragma unroll
    for (int j = 0; j < 4; j++) {
        int cb = cq * 32 + j * 8;
        float4 s0 = *(const float4*)&asw[cb], s1 = *(const float4*)&asw[cb + 4];
        float4 d0 = *(const float4*)&adw[cb], d1 = *(const float4*)&adw[cb + 4];
        ps = fmaf((float)hv[j][0], s0.x, ps); pd = fmaf((float)hv[j][0], d0.x, pd);
        ps = fmaf((float)hv[j][1], s0.y, ps); pd = fmaf((float)hv[j][1], d0.y, pd);
        ps = fmaf((float)hv[j][2], s0.z, ps); pd = fmaf((float)hv[j][2], d0.z, pd);
        ps = fmaf((float)hv[j][3], s0.w, ps); pd = fmaf((float)hv[j][3], d0.w, pd);
        ps = fmaf((float)hv[j][4], s1.x, ps); pd = fmaf((float)hv[j][4], d1.x, pd);
        ps = fmaf((float)hv[j][5], s1.y, ps); pd = fmaf((float)hv[j][5], d1.y, pd);
        ps = fmaf((float)hv[j][6], s1.z, ps); pd = fmaf((float)hv[j][6], d1.z, pd);
        ps = fmaf((float)hv[j][7], s1.w, ps); pd = fmaf((float)hv[j][7], d1.w, pd);
    }
    ps += __shfl_xor(ps, 1); ps += __shfl_xor(ps, 2);
    pd += __shfl_xor(pd, 1); pd += __shfl_xor(pd, 2);
    if (node < N) {
        #pragma unroll
        for (int j = 0; j < 4; j++)
            *(half8*)&g2h[(size_t)node * 128 + cq * 32 + j * 8] = hv[j];
        if (cq == 0) { as2[node] = ps; ad2[node] = pd; }
    }
}

// ---------- Layer 2 aggregation: FOUR nodes per wave (quarter-wave each),
//            16 lanes x 16B gathers, 4-edge unrolled ----------
__global__ void k_agg2(const int* __restrict__ rp, const int* __restrict__ esrc,
                       const float* __restrict__ as2, const float* __restrict__ ad2,
                       const _Float16* __restrict__ g2h, const float* __restrict__ b2,
                       _Float16* __restrict__ out2h, int N) {
    int wid = threadIdx.x >> 6, lane = threadIdx.x & 63;
    int qtr = lane >> 4, sl16 = lane & 15;
    int n = blockIdx.x * 16 + wid * 4 + qtr;
    if (n >= N) return;
    int beg = rp[n], end = rp[n + 1];
    float ad = ad2[n];
    int qbase = qtr << 4;
    float a[8];
    #pragma unroll
    for (int i = 0; i < 8; i++) a[i] = 0.f;
    float den = 0.f;
    for (int t0 = beg; t0 < end; t0 += 16) {
        int k = t0 + sl16;
        int sl = 0; float wl = 0.f;
        if (k < end) {
            sl = esrc[k];
            float e = as2[sl] + ad;
            e = e > 0.f ? e : NEG_SLOPE * e;
            wl = __expf(e);
        }
        int nt = min(16, end - t0);
        int k2 = 0;
        for (; k2 + 3 < nt; k2 += 4) {
            float w0 = __shfl(wl, qbase + k2),     w1 = __shfl(wl, qbase + k2 + 1);
            float w2 = __shfl(wl, qbase + k2 + 2), w3 = __shfl(wl, qbase + k2 + 3);
            int   s0 = __shfl(sl, qbase + k2),     s1 = __shfl(sl, qbase + k2 + 1);
            int   s2 = __shfl(sl, qbase + k2 + 2), s3 = __shfl(sl, qbase + k2 + 3);
            half8 g0 = ((const half8*)g2h)[(size_t)s0 * 16 + sl16];
            half8 g1 = ((const half8*)g2h)[(size_t)s1 * 16 + sl16];
            half8 g2 = ((const half8*)g2h)[(size_t)s2 * 16 + sl16];
            half8 g3 = ((const half8*)g2h)[(size_t)s3 * 16 + sl16];
            den += (w0 + w1) + (w2 + w3);
            #pragma unroll
            for (int i = 0; i < 8; i++) {
                a[i] = fmaf(w0, (float)g0[i], a[i]);
                a[i] = fmaf(w1, (float)g1[i], a[i]);
                a[i] = fmaf(w2, (float)g2[i], a[i]);
                a[i] = fmaf(w3, (float)g3[i], a[i]);
            }
        }
        for (; k2 < nt; k2++) {
            float w = __shfl(wl, qbase + k2);
            int s = __shfl(sl, qbase + k2);
            half8 gv = ((const half8*)g2h)[(size_t)s * 16 + sl16];
            den += w;
            #pragma unroll
            for (int i = 0; i < 8; i++) a[i] = fmaf(w, (float)gv[i], a[i]);
        }
    }
    float inv = 1.f / (den + 1e-16f);
    float4 b0 = *(const float4*)&b2[sl16 * 8];
    float4 b1v = *(const float4*)&b2[sl16 * 8 + 4];
    half8 ov;
    ov[0] = (_Float16)(a[0] * inv + b0.x);
    ov[1] = (_Float16)(a[1] * inv + b0.y);
    ov[2] = (_Float16)(a[2] * inv + b0.z);
    ov[3] = (_Float16)(a[3] * inv + b0.w);
    ov[4] = (_Float16)(a[4] * inv + b1v.x);
    ov[5] = (_Float16)(a[5] * inv + b1v.y);
    ov[6] = (_Float16)(a[6] * inv + b1v.z);
    ov[7] = (_Float16)(a[7] * inv + b1v.w);
    *(half8*)&out2h[(size_t)n * 128 + sl16 * 8] = ov;
}

// ---------- BN2 stats: vectorized half8 loads ----------
__global__ void k_bnstats(const _Float16* __restrict__ v, int N,
                          float* __restrict__ sum, float* __restrict__ sq) {
    __shared__ float wred[4][16][16];
    int t = threadIdx.x;
    int rr = t >> 4, cg = t & 15;
    int rows = (N + gridDim.x - 1) / gridDim.x;
    int r0 = blockIdx.x * rows, r1 = min(N, r0 + rows);
    float s[8], q[8];
    #pragma unroll
    for (int i = 0; i < 8; i++) { s[i] = 0.f; q[i] = 0.f; }
    for (int r = r0 + rr; r < r1; r += 16) {
        half8 hv = *(const half8*)&v[(size_t)r * 128 + cg * 8];
        #pragma unroll
        for (int i = 0; i < 8; i++) {
            float xx = (float)hv[i];
            s[i] += xx; q[i] = fmaf(xx, xx, q[i]);
        }
    }
    #pragma unroll
    for (int i = 0; i < 8; i++) {
        s[i] += __shfl_xor(s[i], 16); s[i] += __shfl_xor(s[i], 32);
        q[i] += __shfl_xor(q[i], 16); q[i] += __shfl_xor(q[i], 32);
    }
    int wave = t >> 6, lane = t & 63;
    if (lane < 16) {
        #pragma unroll
        for (int i = 0; i < 8; i++) {
            wred[wave][lane][i] = s[i];
            wred[wave][lane][8 + i] = q[i];
        }
    }
    __syncthreads();
    {
        int cg2 = t >> 4, e = t & 15;
        float tot = wred[0][cg2][e] + wred[1][cg2][e] + wred[2][cg2][e] + wred[3][cg2][e];
        if (e < 8) atomicAdd(&sum[cg2 * 8 + e], tot);
        else       atomicAdd(&sq[cg2 * 8 + e - 8], tot);
    }
}

// ---------- pooling: one block per (graph, quarter); vectorized ----------
__global__ void k_poolg2(const _Float16* __restrict__ v, const int* __restrict__ gb,
                         const float* __restrict__ bnsum, const float* __restrict__ bnsq,
                         const float* __restrict__ gamma, const float* __restrict__ beta,
                         float* __restrict__ out, int N) {
    __shared__ float wred[4][16][8];
    int t = threadIdx.x;
    int g = blockIdx.x >> 2, qtr = blockIdx.x & 3;
    int rr = t >> 4, cg = t & 15;
    int gs = gb[g], ge = gb[g + 1];
    int len = ge - gs;
    int q0 = gs + (len * qtr) / 4, q1 = gs + (len * (qtr + 1)) / 4;
    float sc[8], sh[8];
    #pragma unroll
    for (int i = 0; i < 8; i++) {
        int j = cg * 8 + i;
        float mu = bnsum[j] / N;
        float var = bnsq[j] / N - mu * mu;
        sc[i] = rsqrtf(var + BN_EPS) * gamma[j];
        sh[i] = beta[j] - mu * sc[i];
    }
    float acc[8];
    #pragma unroll
    for (int i = 0; i < 8; i++) acc[i] = 0.f;
    for (int r = q0 + rr; r < q1; r += 16) {
        half8 hv = *(const half8*)&v[(size_t)r * 128 + cg * 8];
        #pragma unroll
        for (int i = 0; i < 8; i++) {
            float y = fmaf((float)hv[i], sc[i], sh[i]);
            acc[i] += y > 0.f ? y : (__expf(y) - 1.0f);
        }
    }
    #pragma unroll
    for (int i = 0; i < 8; i++) {
        acc[i] += __shfl_xor(acc[i], 16);
        acc[i] += __shfl_xor(acc[i], 32);
    }
    int wave = t >> 6, lane = t & 63;
    if (lane < 16) {
        #pragma unroll
        for (int i = 0; i < 8; i++) wred[wave][lane][i] = acc[i];
    }
    __syncthreads();
    if (t < 128) {
        int cg2 = t >> 3, e = t & 7;
        float tot = wred[0][cg2][e] + wred[1][cg2][e] + wred[2][cg2][e] + wred[3][cg2][e];
        float invc = 1.f / fmaxf((float)len, 1.0f);
        atomicAdd(&out[(size_t)g * 128 + cg2 * 8 + e], tot * invc);
    }
}

extern "C" void kernel_launch(void* const* d_in, const int* in_sizes, int n_in,
                              void* d_out, int out_size, void* d_ws, size_t ws_size,
                              hipStream_t stream) {
    const float* x     = (const float*)d_in[0];
    const int*   ei    = (const int*)d_in[1];
    const int*   batch = (const int*)d_in[2];
    const float* W1    = (const float*)d_in[4];
    const float* asw1  = (const float*)d_in[5];
    const float* adw1  = (const float*)d_in[6];
    const float* b1    = (const float*)d_in[7];
    const float* gamma1= (const float*)d_in[8];
    const float* beta1 = (const float*)d_in[9];
    const float* W2    = (const float*)d_in[10];
    const float* asw2  = (const float*)d_in[11];
    const float* adw2  = (const float*)d_in[12];
    const float* b2    = (const float*)d_in[13];
    const float* gamma2= (const float*)d_in[14];
    const float* beta2 = (const float*)d_in[15];
    float* out = (float*)d_out;

    const int N  = in_sizes[2];
    const int E  = in_sizes[1] / 2;
    const int E2 = E + N;
    const int G  = out_size / 128;

    char* ws = (char*)d_ws;
    size_t off = 0;
    auto A = [&](size_t bytes) { size_t o = off; off += (bytes + 255) & ~(size_t)255; return o; };
    _Float16* g2h  = (_Float16*)(ws + A((size_t)N * 128 * 2));
    _Float16* w2t  = (_Float16*)(ws + A((size_t)128 * 256 * 2));
    _Float16* out2h= (_Float16*)(ws + A((size_t)N * 128 * 2));
    float* uv    = (float*)(ws + A((size_t)N * 8 * 4));
    float* as2   = (float*)(ws + A((size_t)N * 4));
    float* ad2   = (float*)(ws + A((size_t)N * 4));
    float* coef  = (float*)(ws + A(16 * 4));
    int*   gb    = (int*)(ws + A((size_t)(G + 1) * 4));
    int*   rp    = (int*)(ws + A((size_t)(N + 1) * 4));
    int*   esrc  = (int*)(ws + A((size_t)E2 * 4));
    int*   bsums = (int*)(ws + A((size_t)((N + 1023) / 1024) * 4));
    size_t zbytes = ((size_t)N + 20 + 256 + 256) * 4;
    size_t zoff = A(zbytes);
    int*   cnt   = (int*)(ws + zoff);
    float* stats = (float*)(cnt + N);
    float* bnsum = stats + 20;
    float* bnsq  = bnsum + 256;

    const int nb = (N + 1023) / 1024;

    // 1: zero scratch AND the full output buffer
    int n4 = (int)((zbytes + 15) / 16);
    int m4 = (out_size + 3) / 4;
    k_zero<<<(n4 + m4 + 255) / 256, 256, 0, stream>>>((uint4*)(ws + zoff), n4,
                                                      (uint4*)out, m4);

    // 2: setup
    int degBlocks = (E2 + 255) / 256;
    k_setup<<<34 + degBlocks, 256, 0, stream>>>(W1, asw1, adw1, coef, W2, w2t,
                                                batch, N, G, gb, ei, E, E2, cnt);

    // 3-4: hierarchical scan -> rp
    k_scan1<<<nb, 1024, 0, stream>>>(cnt, rp, bsums, N);
    k_scan2f<<<nb, 1024, 0, stream>>>(rp, bsums, N, E2, nb);

    // 5: scatter
    k_scatter<<<degBlocks, 256, 0, stream>>>(ei, E, E2, rp, cnt, esrc);

    // 6: layer-1 rank-2 aggregation + BN1 stats
    k_agg1r<<<(N + 255) / 256, 256, 0, stream>>>(rp, esrc, x, coef, uv, stats, N);

    // 7: layer-2 GEMM via MFMA
    k_gemm2<<<(N + 127) / 128, 512, 0, stream>>>(uv, stats, W1, b1, gamma1, beta1,
                                                 w2t, asw2, adw2, g2h, as2, ad2, N);

    // 8: layer-2 aggregation (4 nodes/wave, 16B gathers, 4-edge unrolled)
    k_agg2<<<(N + 15) / 16, 256, 0, stream>>>(rp, esrc, as2, ad2, g2h, b2, out2h, N);

    // 9: BN2 stats
    k_bnstats<<<512, 256, 0, stream>>>(out2h, N, bnsum, bnsq);

    // 10: pooling
    k_poolg2<<<G * 4, 256, 0, stream>>>(out2h, gb, bnsum, bnsq, gamma2, beta2, out, N);
}